// Round 5
// baseline (3161.729 us; speedup 1.0000x reference)
//
#include <hip/hip_runtime.h>
#include <stdint.h>

// Problem: V=50000, D=256, H=512, B=64, T=512.  out = stack([c_final, h_final]) fp32 [2,64,512]
// R4b: 32 persistent WGs (cooperative), each owns 16 hidden units (64 gate cols).
//   W strip [768,64] bf16 (96 KB) in LDS, gate-major fragment order (acc_g = gate g).
//   h exchange: sc0 sc1 (LLC-coherent, L1/L2-bypass) stores + distributed per-WG flags,
//   divergent-masked polling. x(t+1) register-prefetched (plain cached loads) during
//   the sync window. Direct per-thread h epilogue (no LDS staging barrier).
//   Fix vs R4: plain `s_waitcnt vmcnt(0)` clobber-fence (no tied asm operands).

#define NWG     32
#define NTHR    256
#define TSTEPS  512
#define BATCH   64
#define EDIM    256
#define HID     512
#define GCOLS   2048

typedef __attribute__((ext_vector_type(8))) short short8;
typedef __attribute__((ext_vector_type(4))) float f32x4;

// ws layout:
//   256    : flags[32], one unsigned per 128 B
//   8448   : hbuf0 (64*512 ushort = 65536 B)
//   73984  : hbuf1
//   139520 : xb bf16 [t][b][d] (16.8 MB)  -- only if ws_size permits

__device__ __forceinline__ unsigned short f2bf(float f) {
  unsigned u = __float_as_uint(f);
  unsigned r = (u + 0x7FFFu + ((u >> 16) & 1u)) >> 16;  // RNE
  return (unsigned short)r;
}
__device__ __forceinline__ float sigf(float x) {
  x = fminf(fmaxf(x, -30.0f), 30.0f);
  return 1.0f / (1.0f + __expf(-x));
}
__device__ __forceinline__ float tanh_fast(float x) {
  x = fminf(fmaxf(x, -15.0f), 15.0f);
  float e = __expf(-2.0f * x);
  return (1.0f - e) / (1.0f + e);
}

__global__ void init_ws(unsigned* ws, int nwords) {
  int i = blockIdx.x * 256 + threadIdx.x;
  if (i < nwords) ws[i] = 0u;
}

// one block per (t,b): gather embedding row, convert to bf16, write xb[t][b][:]
__global__ void embed_k(const int* __restrict__ widx, const float* __restrict__ Wemb,
                        unsigned short* __restrict__ xb) {
  int tb = blockIdx.x;                 // t*64 + b
  int t = tb >> 6, b = tb & 63;
  int wi = widx[b * TSTEPS + t];       // word_indices is [B,T]
  const float* src = Wemb + (size_t)wi * EDIM + threadIdx.x * 4;
  float4 v = *(const float4*)src;
  ushort4 o;
  o.x = f2bf(v.x); o.y = f2bf(v.y); o.z = f2bf(v.z); o.w = f2bf(v.w);
  *(ushort4*)(xb + (size_t)tb * EDIM + threadIdx.x * 4) = o;
}

__launch_bounds__(NTHR, 1)
__global__ void lstm_persist(const int* __restrict__ num_words,
                             const int* __restrict__ widx,
                             const float* __restrict__ Wemb,
                             const float* __restrict__ Wk,
                             const float* __restrict__ bias,
                             const unsigned short* __restrict__ xb,
                             unsigned short* __restrict__ hb0,
                             unsigned short* __restrict__ hb1,
                             unsigned* flags,
                             float* __restrict__ out,
                             int has_xb)
{
  // W strip fragment order: frag q = (g*24 + kk)*64 + lane holds 8 bf16:
  //   B[k = kk*32 + (lane>>4)*8 + j][gcol = g*512 + u0 + (lane&15)]
  __shared__ alignas(16) short Wlds[49152];      // 96 KB
  __shared__ float gsc[4352];                    // 4 waves * 16 rows * stride 68
  __shared__ float blds[64];

  const int tid = threadIdx.x;
  const int u0  = blockIdx.x * 16;               // this WG's hidden units u0..u0+15

  for (int q = tid; q < 6144; q += NTHR) {
    int g   = q / 1536;                          // 24*64
    int rem = q - g * 1536;
    int kk  = rem >> 6;
    int lq  = rem & 63;
    int kbase = kk * 32 + ((lq >> 4) << 3);
    int gcol  = (g << 9) + u0 + (lq & 15);
    short8 v;
#pragma unroll
    for (int j = 0; j < 8; ++j)
      v[j] = (short)f2bf(Wk[(size_t)(kbase + j) * GCOLS + gcol]);
    *(short8*)&Wlds[q * 8] = v;
  }
  if (tid < 64) blds[tid] = bias[((tid >> 4) << 9) + u0 + (tid & 15)];

  // MFMA geometry: wave wv owns batches wv*16..+15 (M tile), 4 N tiles (= gates i,j,f,o).
  const int wv   = tid >> 6;
  const int lane = tid & 63;
  const int bb   = wv * 16 + (lane & 15);        // A-row (batch) this lane loads
  const int kq   = (lane >> 4) << 3;             // k sub-offset 0/8/16/24

  // epilogue ownership: thread handles batch eb, units u0 + uq*4 .. +3
  const int eb = tid >> 2, uq = tid & 3;
  const int nwb = num_words[eb];
  float cst[4] = {0.f, 0.f, 0.f, 0.f};
  float hsv[4] = {0.f, 0.f, 0.f, 0.f};

  __syncthreads();

  const float bI[4] = {blds[uq*4+0], blds[uq*4+1], blds[uq*4+2], blds[uq*4+3]};
  const float bJ[4] = {blds[16+uq*4+0], blds[16+uq*4+1], blds[16+uq*4+2], blds[16+uq*4+3]};
  const float bF[4] = {blds[32+uq*4+0], blds[32+uq*4+1], blds[32+uq*4+2], blds[32+uq*4+3]};
  const float bO[4] = {blds[48+uq*4+0], blds[48+uq*4+1], blds[48+uq*4+2], blds[48+uq*4+3]};

  unsigned short* hb[2] = {hb0, hb1};

  uint4 xf[8];
  if (has_xb) {   // prologue: issue x(0) loads
    const unsigned short* xr = xb + (size_t)bb * EDIM + kq;
#pragma unroll
    for (int kk = 0; kk < 8; ++kk)
      asm volatile("global_load_dwordx4 %0, %1, off" : "=v"(xf[kk]) : "v"(xr + kk * 32));
  }

  for (int t = 0; t < TSTEPS; ++t) {
    f32x4 acc[4];
    acc[0] = (f32x4){0.f,0.f,0.f,0.f}; acc[1] = (f32x4){0.f,0.f,0.f,0.f};
    acc[2] = (f32x4){0.f,0.f,0.f,0.f}; acc[3] = (f32x4){0.f,0.f,0.f,0.f};

    // ---- x part (k = 0..255): consume prefetched regs, then prefetch x(t+1) ----
    if (has_xb) {
      asm volatile("s_waitcnt vmcnt(0)" ::: "memory");
#pragma unroll
      for (int kk = 0; kk < 8; ++kk) {
        short8 a = __builtin_bit_cast(short8, xf[kk]);
#pragma unroll
        for (int g = 0; g < 4; ++g) {
          short8 w = *(const short8*)&Wlds[((g * 24 + kk) * 64 + lane) * 8];
          acc[g] = __builtin_amdgcn_mfma_f32_16x16x32_bf16(a, w, acc[g], 0, 0, 0);
        }
      }
      int tn = (t + 1 < TSTEPS) ? t + 1 : t;
      const unsigned short* xr = xb + ((size_t)tn * BATCH + bb) * EDIM + kq;
#pragma unroll
      for (int kk = 0; kk < 8; ++kk)
        asm volatile("global_load_dwordx4 %0, %1, off" : "=v"(xf[kk]) : "v"(xr + kk * 32));
    } else {
      int wi = widx[bb * TSTEPS + t];
      const float* erow = Wemb + (size_t)wi * EDIM + kq;
#pragma unroll
      for (int kk = 0; kk < 8; ++kk) {
        float4 f0 = *(const float4*)(erow + kk * 32);
        float4 f1 = *(const float4*)(erow + kk * 32 + 4);
        short8 a;
        a[0] = (short)f2bf(f0.x); a[1] = (short)f2bf(f0.y);
        a[2] = (short)f2bf(f0.z); a[3] = (short)f2bf(f0.w);
        a[4] = (short)f2bf(f1.x); a[5] = (short)f2bf(f1.y);
        a[6] = (short)f2bf(f1.z); a[7] = (short)f2bf(f1.w);
#pragma unroll
        for (int g = 0; g < 4; ++g) {
          short8 w = *(const short8*)&Wlds[((g * 24 + kk) * 64 + lane) * 8];
          acc[g] = __builtin_amdgcn_mfma_f32_16x16x32_bf16(a, w, acc[g], 0, 0, 0);
        }
      }
    }

    // ---- wait: all WGs' flags >= t; divergent-masked poll (lanes drop out) ----
    if (t > 0) {
      if (tid < NWG) {
        const unsigned* fp = flags + (tid << 5);
        const unsigned tgt = (unsigned)t;
        unsigned v;
        do {
          asm volatile("global_load_dword %0, %1, off sc0 sc1\n\t"
                       "s_waitcnt vmcnt(0)"
                       : "=v"(v) : "v"(fp));
        } while (v < tgt);
      }
      __syncthreads();
    }

    // ---- h part (k = 256..767): batched LLC-coherent loads, one drain, then MFMAs ----
    {
      const unsigned short* hrow = hb[t & 1] + bb * HID + kq;
      uint4 af[16];
#pragma unroll
      for (int kk = 0; kk < 16; ++kk)
        asm volatile("global_load_dwordx4 %0, %1, off sc0 sc1"
                     : "=v"(af[kk]) : "v"(hrow + kk * 32));
      asm volatile("s_waitcnt vmcnt(8)" ::: "memory");   // xf prefetch may still be in flight
      asm volatile("s_waitcnt vmcnt(0)" ::: "memory");
#pragma unroll
      for (int kk = 0; kk < 16; ++kk) {
        short8 a = __builtin_bit_cast(short8, af[kk]);
#pragma unroll
        for (int g = 0; g < 4; ++g) {
          short8 w = *(const short8*)&Wlds[((g * 24 + 8 + kk) * 64 + lane) * 8];
          acc[g] = __builtin_amdgcn_mfma_f32_16x16x32_bf16(a, w, acc[g], 0, 0, 0);
        }
      }
    }

    // ---- C/D (col=lane&15, row=(lane>>4)*4+reg) -> LDS gate-major scratch ----
#pragma unroll
    for (int r = 0; r < 4; ++r) {
      int row = ((lane >> 4) << 2) + r;
      float* dst = &gsc[wv * 1088 + row * 68 + (lane & 15)];
      dst[0]  = acc[0][r];
      dst[16] = acc[1][r];
      dst[32] = acc[2][r];
      dst[48] = acc[3][r];
    }
    __syncthreads();

    // ---- epilogue: 4 units per thread, direct register h ----
    {
      const float* g0 = &gsc[(eb >> 4) * 1088 + (eb & 15) * 68 + uq * 4];
      float4 gI = *(const float4*)(g0);
      float4 gJ = *(const float4*)(g0 + 16);
      float4 gF = *(const float4*)(g0 + 32);
      float4 gO = *(const float4*)(g0 + 48);
      float gi[4] = {gI.x, gI.y, gI.z, gI.w};
      float gj[4] = {gJ.x, gJ.y, gJ.z, gJ.w};
      float gf[4] = {gF.x, gF.y, gF.z, gF.w};
      float go[4] = {gO.x, gO.y, gO.z, gO.w};
      bool live = (t < nwb);
#pragma unroll
      for (int m = 0; m < 4; ++m) {
        float cn = sigf(gf[m] + bF[m] + 1.0f) * cst[m] +
                   sigf(gi[m] + bI[m]) * tanh_fast(gj[m] + bJ[m]);
        float hn = sigf(go[m] + bO[m]) * tanh_fast(cn);
        if (live) { cst[m] = cn; hsv[m] = hn; }
      }
    }

    // ---- arrive: direct write-through h, drain, barrier, flag ----
    if (t + 1 < TSTEPS) {
      unsigned short* hw = hb[(t + 1) & 1];
      unsigned lo = (unsigned)f2bf(hsv[0]) | ((unsigned)f2bf(hsv[1]) << 16);
      unsigned hi = (unsigned)f2bf(hsv[2]) | ((unsigned)f2bf(hsv[3]) << 16);
      unsigned long long pv = (unsigned long long)lo | ((unsigned long long)hi << 32);
      unsigned* dst = (unsigned*)(hw + (size_t)eb * HID + u0 + uq * 4);
      asm volatile("global_store_dwordx2 %0, %1, off sc0 sc1"
                   :: "v"(dst), "v"(pv) : "memory");
      asm volatile("s_waitcnt vmcnt(0)" ::: "memory");
      __syncthreads();                           // all waves' h drained
      if (tid == 0) {
        unsigned* fa = flags + ((unsigned)blockIdx.x << 5);
        unsigned fv = (unsigned)(t + 1);
        asm volatile("global_store_dword %0, %1, off sc0 sc1"
                     :: "v"(fa), "v"(fv) : "memory");
      }
    }
  }

  // final state: out[0][b][h]=c, out[1][b][h]=h
  {
    float* oc = out + eb * HID + u0 + uq * 4;
    float* oh = out + 32768 + eb * HID + u0 + uq * 4;
    *(float4*)oc = (float4){cst[0], cst[1], cst[2], cst[3]};
    *(float4*)oh = (float4){hsv[0], hsv[1], hsv[2], hsv[3]};
  }
}

extern "C" void kernel_launch(void* const* d_in, const int* in_sizes, int n_in,
                              void* d_out, int out_size, void* d_ws, size_t ws_size,
                              hipStream_t stream) {
  const int*   widx = (const int*)d_in[0];
  const int*   nw   = (const int*)d_in[1];
  const float* Wemb = (const float*)d_in[2];
  const float* Wk   = (const float*)d_in[3];
  const float* bias = (const float*)d_in[4];
  float* out = (float*)d_out;
  char* ws = (char*)d_ws;

  unsigned* flags = (unsigned*)(ws + 256);
  unsigned short* hb0 = (unsigned short*)(ws + 8448);
  unsigned short* hb1 = (unsigned short*)(ws + 73984);
  unsigned short* xb  = (unsigned short*)(ws + 139520);

  size_t need = 139520ull + (size_t)TSTEPS * BATCH * EDIM * 2;
  int has_xb = (ws_size >= need) ? 1 : 0;

  size_t init_bytes = ws_size < 139520ull ? ws_size : 139520ull;
  int init_words = (int)(init_bytes / 4);
  init_ws<<<(init_words + 255) / 256, 256, 0, stream>>>((unsigned*)ws, init_words);
  if (has_xb)
    embed_k<<<TSTEPS * BATCH, 64, 0, stream>>>(widx, Wemb, xb);

  void* args[] = {(void*)&nw, (void*)&widx, (void*)&Wemb, (void*)&Wk, (void*)&bias,
                  (void*)&xb, (void*)&hb0, (void*)&hb1, (void*)&flags,
                  (void*)&out, (void*)&has_xb};
  (void)hipLaunchCooperativeKernel((void*)lstm_persist, dim3(NWG), dim3(NTHR), args, 0, stream);
}